// Round 24
// baseline (95.538 us; speedup 1.0000x reference)
//
#include <hip/hip_runtime.h>
#include <stdint.h>

typedef unsigned short u16;
typedef uint32_t u32;
typedef __bf16 bf16;
typedef bf16 bf16x8 __attribute__((ext_vector_type(8)));
typedef bf16 bf16x4 __attribute__((ext_vector_type(4)));
typedef short s16x4 __attribute__((ext_vector_type(4)));
typedef float f32x4 __attribute__((ext_vector_type(4)));
typedef uint32_t u32x4 __attribute__((ext_vector_type(4)));

// ---- constants: B=4, S=4096, D_IN=768, D_OUT=128 ----
#define S_LEN 4096
#define D_IN 768
#define D_OUT 128
#define NB 4
#define M_TOTAL (NB * S_LEN) // 16384
#define NPROP 115            // proportional-split blocks per batch

// proportional KV-split tables: tile t (of 16, 256 rows) has nj=4t+4 KV tiles and
// SPLITS[t]=ceil(nj/5) splits -> every block runs 4-5 iterations (uniform load).
__device__ const unsigned char SPLITS_T[16] = {1,2,3,4,4,5,6,7,8,8,9,10,11,12,12,13};
__device__ const unsigned char OFF_T[16]    = {0,1,3,6,10,14,19,25,32,40,48,57,67,78,90,102};
__device__ const unsigned char TILE_OF[NPROP] = {
    0, 1,1, 2,2,2, 3,3,3,3, 4,4,4,4, 5,5,5,5,5, 6,6,6,6,6,6, 7,7,7,7,7,7,7,
    8,8,8,8,8,8,8,8, 9,9,9,9,9,9,9,9, 10,10,10,10,10,10,10,10,10,
    11,11,11,11,11,11,11,11,11,11, 12,12,12,12,12,12,12,12,12,12,12,
    13,13,13,13,13,13,13,13,13,13,13,13, 14,14,14,14,14,14,14,14,14,14,14,14,
    15,15,15,15,15,15,15,15,15,15,15,15,15};

static __device__ __forceinline__ u16 f2bf(float f) {
    union { float f; uint32_t u; } c; c.f = f;
    return (u16)((c.u + 0x7FFFu + ((c.u >> 16) & 1u)) >> 16);
}
static __device__ __forceinline__ float bf2f_lo(uint32_t w) { return __uint_as_float(w << 16); }
static __device__ __forceinline__ float bf2f_hi(uint32_t w) { return __uint_as_float(w & 0xFFFF0000u); }

static __device__ __forceinline__ bf16x8 ld8(const u16* p) {
    union { u32x4 v; bf16x8 b; } c;
    c.v = *reinterpret_cast<const u32x4*>(p);
    return c.b;
}

static __device__ __forceinline__ f32x4 mfma16(bf16x8 a, bf16x8 b, f32x4 c) {
    return __builtin_amdgcn_mfma_f32_16x16x32_bf16(a, b, c, 0, 0, 0);
}

// 16x16x16 bf16 MFMA: B-layout == 16x16 D-layout (S^T feeds PV with no cross-lane ops).
// Guard with __HIP_DEVICE_COMPILE__: __has_builtin is false in the host pass (R15).
static __device__ __forceinline__ f32x4 mfma16k16(uint2 a, uint2 b, f32x4 c) {
#if defined(__HIP_DEVICE_COMPILE__)
#if __has_builtin(__builtin_amdgcn_mfma_f32_16x16x16_bf16)
    union { uint2 u; bf16x4 v; } ca, cb; ca.u = a; cb.u = b;
    return __builtin_amdgcn_mfma_f32_16x16x16_bf16(ca.v, cb.v, c, 0, 0, 0);
#else
    union { uint2 u; s16x4 v; } ca, cb; ca.u = a; cb.u = b;
    return __builtin_amdgcn_mfma_f32_16x16x16bf16_1k(ca.v, cb.v, c, 0, 0, 0);
#endif
#else
    (void)a; (void)b;
    return c; // host pass stub -- never executed
#endif
}

// async global->LDS, 16B per lane; dest = uniform base + lane*16 (linear)
static __device__ __forceinline__ void gload16(const void* g, void* l) {
    __builtin_amdgcn_global_load_lds((const __attribute__((address_space(1))) uint32_t*)g,
                                     (__attribute__((address_space(3))) uint32_t*)l, 16, 0, 0);
}

static __device__ __forceinline__ float bpermf(int addr, float v) {
    return __int_as_float(__builtin_amdgcn_ds_bpermute(addr, __float_as_int(v)));
}
// truncating bf16 pack: low16 = bf16(a), high16 = bf16(b), one v_perm_b32
static __device__ __forceinline__ u32 pk2(float a, float b) {
    return __builtin_amdgcn_perm(__float_as_uint(b), __float_as_uint(a), 0x07060302u);
}

// ---------------- Kernel 1: W -> W^T bf16 via LDS transpose ----------------
__global__ __launch_bounds__(256) void wt_kernel(const float* __restrict__ Wq, const float* __restrict__ Wk,
                                                 const float* __restrict__ Wv, u16* __restrict__ Wt) {
    __shared__ u16 tl[128][40];
    const int w = blockIdx.x / 24;
    const int kc = (blockIdx.x % 24) * 32;
    const float* W = (w == 0) ? Wq : (w == 1) ? Wk : Wv;
#pragma unroll
    for (int p = 0; p < 4; ++p) {
        int kr = p * 8 + (threadIdx.x >> 5);
        int nc = (threadIdx.x & 31) * 4;
        float4 v = *reinterpret_cast<const float4*>(W + (size_t)(kc + kr) * D_OUT + nc);
        tl[nc + 0][kr] = f2bf(v.x); tl[nc + 1][kr] = f2bf(v.y);
        tl[nc + 2][kr] = f2bf(v.z); tl[nc + 3][kr] = f2bf(v.w);
    }
    __syncthreads();
    const int n = threadIdx.x >> 1, kh = (threadIdx.x & 1) * 16;
    u32x4* dst = reinterpret_cast<u32x4*>(Wt + (size_t)w * D_OUT * D_IN + (size_t)n * D_IN + kc + kh);
    const u32x4* src = reinterpret_cast<const u32x4*>(&tl[n][kh]);
    dst[0] = src[0];
    dst[1] = src[1];
}

// ---------------- Kernel 2: fused QKV projection, 6-way output split, K-step 64 ----------------
// grid (256,6), block 256 (4 waves x 16 rows); block = 64 rows x 64 cols x one of
// Q/K/V (y=by>>1) x col-half (h=by&1). 1536 blocks = 5 blocks/CU at 32KB LDS
// (R23: 3 blocks/CU at 48KB -> 33us; co-resident-block count is the proven lever).
// W dbuf 2x8KB + x bf16-packed dbuf 2x8KB; single barrier/iter, 8 MFMA/wave/iter.
__global__ __launch_bounds__(256) void qkv_kernel(const float* __restrict__ x, const u16* __restrict__ Wt,
                                                  u16* __restrict__ Qb, u16* __restrict__ Kb,
                                                  u16* __restrict__ Vt) {
    __shared__ __align__(16) u16 wslab[2][64 * 64]; // [col'][64k] bf16, slot^=(row&7)
    __shared__ __align__(16) u16 xslab[2][64 * 64]; // [row][64k] bf16, slot^=(row&7)
    const int wave = threadIdx.x >> 6, lane = threadIdx.x & 63;
    const int r = lane & 15, g = lane >> 4;
    const int m0 = blockIdx.x * 64;
    const int y = (int)blockIdx.y >> 1;   // which of Q/K/V
    const int h = (int)blockIdx.y & 1;    // col-half of 128
    const u16* wt = Wt + (size_t)y * D_OUT * D_IN;

    f32x4 acc[4];
#pragma unroll
    for (int f = 0; f < 4; ++f) acc[f] = f32x4{0.f, 0.f, 0.f, 0.f};

    // stage W[y][h*64..+64 cols][kk*64..+64]: 8 chunks of 1KB (8 rows x 128B)
    auto stageW = [&](int bb, int kk) {
#pragma unroll
        for (int i = 0; i < 2; ++i) {
            int c = i * 4 + wave;                 // 0..7
            int rr = c * 8 + (lane >> 3);         // col' 0..63
            int slot = (lane & 7) ^ (rr & 7);
            const u16* src = wt + (size_t)(h * 64 + rr) * D_IN + kk * 64 + slot * 8;
            gload16(src, &wslab[bb][c * 512]);
        }
    };
    auto loadX = [&](int kk, float4* v) {
        const float* src = x + (size_t)(m0 + (threadIdx.x >> 2)) * D_IN + kk * 64 + (threadIdx.x & 3) * 16;
        v[0] = *reinterpret_cast<const float4*>(src);
        v[1] = *reinterpret_cast<const float4*>(src + 4);
        v[2] = *reinterpret_cast<const float4*>(src + 8);
        v[3] = *reinterpret_cast<const float4*>(src + 12);
    };
    auto writeX = [&](int bb, const float4* v) {
        const int row = threadIdx.x >> 2, w2 = (threadIdx.x & 3) * 2;
        u32x4 p0, p1;
        p0[0] = pk2(v[0].x, v[0].y); p0[1] = pk2(v[0].z, v[0].w);
        p0[2] = pk2(v[1].x, v[1].y); p0[3] = pk2(v[1].z, v[1].w);
        p1[0] = pk2(v[2].x, v[2].y); p1[1] = pk2(v[2].z, v[2].w);
        p1[2] = pk2(v[3].x, v[3].y); p1[3] = pk2(v[3].z, v[3].w);
        *reinterpret_cast<u32x4*>(&xslab[bb][row * 64 + ((w2 ^ (row & 7)) * 8)]) = p0;
        *reinterpret_cast<u32x4*>(&xslab[bb][row * 64 + (((w2 + 1) ^ (row & 7)) * 8)]) = p1;
    };

    float4 xv[4];
    stageW(0, 0);
    loadX(0, xv);
    int buf = 0;
    const int arow = wave * 16 + r;
    for (int kk = 0; kk < 12; ++kk) {
        writeX(buf, xv);
        asm volatile("s_waitcnt lgkmcnt(0)" ::: "memory"); // my ds_writes drained
        asm volatile("s_waitcnt vmcnt(0)" ::: "memory");   // W(buf) DMA done (issued last iter)
        __builtin_amdgcn_sched_barrier(0);
        __builtin_amdgcn_s_barrier();                      // all waves: W(buf)+x(buf) visible
        if (kk + 1 < 12) {
            stageW(buf ^ 1, kk + 1);
            loadX(kk + 1, xv);
        }
#pragma unroll
        for (int kk2 = 0; kk2 < 2; ++kk2) {
            bf16x8 xa = ld8(&xslab[buf][arow * 64 + (((kk2 * 4 + g) ^ (arow & 7)) * 8)]);
#pragma unroll
            for (int f = 0; f < 4; ++f) {
                int rr = f * 16 + r;
                bf16x8 wf = ld8(&wslab[buf][rr * 64 + (((kk2 * 4 + g) ^ (rr & 7)) * 8)]);
                acc[f] = mfma16(xa, wf, acc[f]);
            }
        }
        buf ^= 1;
    }
    asm volatile("s_waitcnt vmcnt(0)" ::: "memory"); // retire-safety (R7 lesson)

    const float QSC = 0.1275174366f; // log2(e)/sqrt(128) folded into Q
    if (y == 0) {
#pragma unroll
        for (int f = 0; f < 4; ++f)
#pragma unroll
            for (int i = 0; i < 4; ++i) {
                int mrow = m0 + wave * 16 + 4 * g + i;
                Qb[(size_t)mrow * D_OUT + h * 64 + f * 16 + r] = f2bf(acc[f][i] * QSC);
            }
    } else if (y == 1) {
#pragma unroll
        for (int f = 0; f < 4; ++f)
#pragma unroll
            for (int i = 0; i < 4; ++i) {
                int mrow = m0 + wave * 16 + 4 * g + i;
                Kb[(size_t)mrow * D_OUT + h * 64 + f * 16 + r] = f2bf(acc[f][i]);
            }
    } else {
#pragma unroll
        for (int f = 0; f < 4; ++f)
#pragma unroll
            for (int i = 0; i < 4; ++i) {
                int mrow = m0 + wave * 16 + 4 * g + i;
                Vt[((size_t)((mrow >> 12) * D_OUT + h * 64 + f * 16 + r)) * S_LEN + (mrow & 4095)] = f2bf(acc[f][i]);
            }
    }
}

// ---------------- Kernel 3: causal flash attention (proportional KV-split, XCD-affine) ----------------
// mode=1: grid 464; b=(n>>1)&3 (XCD affinity), idx=(n>>3)*2+(n&1) selects (t,s).
// mode=0 (ws fallback): grid 64, direct out.
__global__ __launch_bounds__(512, 2) void attn_kernel(const u16* __restrict__ Qb, const u16* __restrict__ Kb,
                                                      const u16* __restrict__ Vt, u16* __restrict__ Po,
                                                      float* __restrict__ Pml, float* __restrict__ out,
                                                      int mode) {
    __shared__ __align__(16) u16 kbuf[2][64 * 128]; // [key][128d], slot^=(row&7)
    __shared__ __align__(16) u16 vbuf[2][128 * 64]; // [d][64key], slot^=(row&7)

    const int wave = threadIdx.x >> 6, lane = threadIdx.x & 63;
    const int r = lane & 15, g = lane >> 4;
    const int n = (int)blockIdx.x;
    int b, t, s, sp, pt;
    if (mode) {
        b = (n >> 1) & 3;                          // XCD batch affinity
        const int idx = (n >> 3) * 2 + (n & 1);
        if (idx >= NPROP) return;
        t = TILE_OF[idx];
        s = idx - OFF_T[t];
        sp = SPLITS_T[t];
        pt = b * NPROP + idx;
    } else {
        b = n >> 4; t = n & 15; s = 0; sp = 1; pt = 0;
    }
    const int nj = 4 * t + 4;
    const int qw0 = t * 256 + wave * 32;

    const u16* Kp = Kb + (size_t)b * S_LEN * D_OUT;
    const u16* Vp = Vt + (size_t)b * D_OUT * S_LEN;

    // Q as B-fragments (col=query on lane&15, k=d)
    bf16x8 qf[2][4];
#pragma unroll
    for (int rb = 0; rb < 2; ++rb)
#pragma unroll
        for (int kk = 0; kk < 4; ++kk)
            qf[rb][kk] = ld8(Qb + ((size_t)(b * S_LEN + qw0 + rb * 16 + r)) * D_OUT + kk * 32 + 8 * g);

    f32x4 o[2][8]; // o[rb][f][i] = O~^T[d=16f+4g+i][q=qw0+rb*16+r]
    float l_[2];
#pragma unroll
    for (int rb = 0; rb < 2; ++rb) {
#pragma unroll
        for (int f = 0; f < 8; ++f) o[rb][f] = f32x4{0.f, 0.f, 0.f, 0.f};
        l_[rb] = 0.f;
    }

    const int lx16 = (lane ^ 16) * 4, lx32 = (lane ^ 32) * 4;

    auto stageK = [&](int bb, int k0) {
#pragma unroll
        for (int i = 0; i < 2; ++i) {
            int c = i * 8 + wave;                 // 0..15, 1KB chunks (4 key-rows)
            int row = c * 4 + (lane >> 4);
            const u16* src = Kp + (size_t)(k0 + row) * D_OUT + (((lane & 15) ^ (row & 7)) * 8);
            gload16(src, &kbuf[bb][c * 512]);
        }
    };
    auto stageV = [&](int bb, int k0) {
#pragma unroll
        for (int i = 0; i < 2; ++i) {
            int c = i * 8 + wave;                 // 0..15, 1KB chunks (8 d-rows)
            int row = c * 8 + (lane >> 3);
            const u16* src = Vp + (size_t)row * S_LEN + k0 + (((lane & 7) ^ (row & 7)) * 8);
            gload16(src, &vbuf[bb][c * 512]);
        }
    };

    stageK(0, s * 64);
    stageV(0, s * 64);
    int buf = 0;
    for (int j = s; j < nj; j += sp) {
        const int k0 = j * 64;
        asm volatile("s_waitcnt vmcnt(0)" ::: "memory"); // stage(buf) done (issued a full iter ago)
        __builtin_amdgcn_sched_barrier(0);
        __builtin_amdgcn_s_barrier();                    // all waves done reading buf^1
        const int j2 = j + sp;
        if (j2 < nj) {                                   // stage next tile into buf^1
            stageK(buf ^ 1, j2 * 64);
            stageV(buf ^ 1, j2 * 64);
        }

        // ---- S^T = K Q : thread holds S^T[key=k0+16f+4g+i][q=qw0+rb*16+r] ----
        f32x4 sv[2][4];
#pragma unroll
        for (int rb = 0; rb < 2; ++rb)
#pragma unroll
            for (int f = 0; f < 4; ++f) sv[rb][f] = f32x4{0.f, 0.f, 0.f, 0.f};
        __builtin_amdgcn_s_setprio(1);
#pragma unroll
        for (int kk = 0; kk < 4; ++kk)
#pragma unroll
            for (int f = 0; f < 4; ++f) {
                bf16x8 kf = ld8(&kbuf[buf][(f * 16 + r) * 128 + (((kk * 4 + g) ^ (r & 7)) * 8)]);
                sv[0][f] = mfma16(kf, qf[0][kk], sv[0][f]);
                sv[1][f] = mfma16(kf, qf[1][kk], sv[1][f]);
            }
        __builtin_amdgcn_s_setprio(0);

        // ---- fixed-base softmax: P = exp2(S); l accumulates per-lane; pack B-frags ----
        uint2 pb[2][4];
#pragma unroll
        for (int rb = 0; rb < 2; ++rb) {
            const int qrb = qw0 + rb * 16;
            const int q = qrb + r;
            if (k0 + 63 > qrb) {
#pragma unroll
                for (int f = 0; f < 4; ++f)
#pragma unroll
                    for (int i = 0; i < 4; ++i)
                        if (k0 + 16 * f + 4 * g + i > q) sv[rb][f][i] = -1e30f; // exp2 -> 0
            }
            float r0 = 0.f;
#pragma unroll
            for (int f = 0; f < 4; ++f)
#pragma unroll
                for (int i = 0; i < 4; ++i) {
                    float p = __builtin_amdgcn_exp2f(sv[rb][f][i]);
                    sv[rb][f][i] = p;
                    r0 += p;
                }
            l_[rb] += r0;
#pragma unroll
            for (int kb = 0; kb < 4; ++kb) {
                pb[rb][kb].x = pk2(sv[rb][kb][0], sv[rb][kb][1]);
                pb[rb][kb].y = pk2(sv[rb][kb][2], sv[rb][kb][3]);
            }
        }

        // ---- O~^T += V^T P^T via 16x16x16 MFMA (A = V^T 4-key slice, B = pb) ----
        __builtin_amdgcn_s_setprio(1);
#pragma unroll
        for (int kb = 0; kb < 4; ++kb) {
            const int vs = ((2 * kb + (g >> 1)) ^ (r & 7)) * 8 + 4 * (g & 1);
#pragma unroll
            for (int f = 0; f < 8; ++f) {
                uint2 vf = *reinterpret_cast<const uint2*>(&vbuf[buf][(f * 16 + r) * 64 + vs]);
                o[0][f] = mfma16k16(vf, pb[0][kb], o[0][f]);
                o[1][f] = mfma16k16(vf, pb[1][kb], o[1][f]);
            }
        }
        __builtin_amdgcn_s_setprio(0);
        buf ^= 1;
    }
    asm volatile("s_waitcnt vmcnt(0)" ::: "memory"); // retire-safety (R7 lesson)

    // finalize l: reduce per-lane partials across the 4 g-groups (once)
    l_[0] += bpermf(lx16, l_[0]);
    l_[1] += bpermf(lx16, l_[1]);
    l_[0] += bpermf(lx32, l_[0]);
    l_[1] += bpermf(lx32, l_[1]);

    if (!mode) {
#pragma unroll
        for (int rb = 0; rb < 2; ++rb) {
            float inv = 1.0f / l_[rb];
            float* orow = out + ((size_t)(b * S_LEN + qw0 + rb * 16 + r)) * D_OUT;
#pragma unroll
            for (int f = 0; f < 8; ++f) {
                float4 v;
                v.x = o[rb][f][0] * inv; v.y = o[rb][f][1] * inv;
                v.z = o[rb][f][2] * inv; v.w = o[rb][f][3] * inv;
                *reinterpret_cast<float4*>(orow + 16 * f + 4 * g) = v;
            }
        }
    } else {
        // wave-coalesced partial layout: chunk (wave,rb,f) = 512B, lane -> base + lane*8B
        u16* po = Po + (size_t)pt * (256 * 128);
        float* pml = Pml + (size_t)pt * 512;
#pragma unroll
        for (int rb = 0; rb < 2; ++rb) {
            u16* chunk0 = po + (size_t)((wave * 2 + rb) * 8) * 256 + lane * 4;
#pragma unroll
            for (int f = 0; f < 8; ++f) {
                u32 w0 = (u32)f2bf(o[rb][f][0]) | ((u32)f2bf(o[rb][f][1]) << 16);
                u32 w1 = (u32)f2bf(o[rb][f][2]) | ((u32)f2bf(o[rb][f][3]) << 16);
                uint2 ww; ww.x = w0; ww.y = w1;
                *reinterpret_cast<uint2*>(chunk0 + f * 256) = ww;
            }
            if (g == 0) {
                const int row = wave * 32 + rb * 16 + r;
                pml[row * 2 + 0] = 0.f;       // unused (fixed base)
                pml[row * 2 + 1] = l_[rb];
            }
        }
    }
}

// ---------------- Kernel 4: split merge (proportional splits, plain sums) ----------------
__global__ __launch_bounds__(256) void merge_kernel(const u16* __restrict__ Po, const float* __restrict__ Pml,
                                                    float* __restrict__ out) {
    const int gr = blockIdx.x * 16 + (threadIdx.x >> 4);
    const int c0 = (threadIdx.x & 15) * 8;
    const int b = gr >> 12, rr = gr & 4095;
    const int t = rr >> 8, row = rr & 255;
    const int ns = SPLITS_T[t];
    const size_t pbase = (size_t)b * NPROP + OFF_T[t];

    // decode (row, c0) -> chunk coords of the attn epilogue layout
    const int wv = row >> 5, rbm = (row >> 4) & 1, r_ = row & 15;
    const int fm = c0 >> 4, g0 = (c0 >> 2) & 3; // g0 in {0,2}
    const size_t coff = (size_t)((wv * 2 + rbm) * 8 + fm) * 256;

    float L = 0.f;
    for (int s = 0; s < ns; ++s) L += Pml[(pbase + s) * 512 + row * 2 + 1];
    const float inv = 1.0f / L;

    float acc[8];
#pragma unroll
    for (int k = 0; k < 8; ++k) acc[k] = 0.f;
    for (int s = 0; s < ns; ++s) {
        const u16* chunk = Po + (pbase + s) * (256 * 128) + coff;
        uint2 pv0 = *reinterpret_cast<const uint2*>(chunk + (g0 * 16 + r_) * 4);
        uint2 pv1 = *reinterpret_cast<const uint2*>(chunk + ((g0 + 1) * 16 + r_) * 4);
        acc[0] += bf2f_lo(pv0.x); acc[1] += bf2f_hi(pv0.x);
        acc[2] += bf2f_lo(pv0.y); acc[3] += bf2f_hi(pv0.y);
        acc[4] += bf2f_lo(pv1.x); acc[5] += bf2f_hi(pv1.x);
        acc[6] += bf2f_lo(pv1.y); acc[7] += bf2f_hi(pv1.y);
    }
    float* op = out + (size_t)gr * D_OUT + c0;
    float4 v0, v1;
    v0.x = acc[0] * inv; v0.y = acc[1] * inv; v0.z = acc[2] * inv; v0.w = acc[3] * inv;
    v1.x = acc[4] * inv; v1.y = acc[5] * inv; v1.z = acc[6] * inv; v1.w = acc[7] * inv;
    *reinterpret_cast<float4*>(op) = v0;
    *reinterpret_cast<float4*>(op + 4) = v1;
}

extern "C" void kernel_launch(void* const* d_in, const int* in_sizes, int n_in,
                              void* d_out, int out_size, void* d_ws, size_t ws_size,
                              hipStream_t stream) {
    const float* x  = (const float*)d_in[0];
    const float* Wq = (const float*)d_in[1];
    const float* Wk = (const float*)d_in[2];
    const float* Wv = (const float*)d_in[3];
    float* out = (float*)d_out;

    // ws layout (u16): Q | K | V^T | W^T | Po | Pml
    u16* Qb = (u16*)d_ws;
    u16* Kb = Qb + (size_t)M_TOTAL * D_OUT;
    u16* Vt = Kb + (size_t)M_TOTAL * D_OUT;
    u16* Wt = Vt + (size_t)M_TOTAL * D_OUT;

    const unsigned long long base = (3ULL * M_TOTAL * D_OUT + 3ULL * D_OUT * D_IN) * 2ULL;
    const unsigned long long perP = 256ULL * 128 * 2 + 512ULL * 4; // Po (64KB) + Pml (2KB)
    const int nblk = NPROP * NB; // 460 partial slots
    const int mode = (ws_size >= base + (unsigned long long)nblk * perP) ? 1 : 0;

    u16* Po = Wt + (size_t)3 * D_OUT * D_IN;
    float* Pml = (float*)(Po + (size_t)nblk * (256 * 128));

    wt_kernel<<<72, 256, 0, stream>>>(Wq, Wk, Wv, Wt);
    qkv_kernel<<<dim3(256, 6), 256, 0, stream>>>(x, Wt, Qb, Kb, Vt);
    attn_kernel<<<mode ? 464 : 16 * NB, 512, 0, stream>>>(Qb, Kb, Vt, Po, Pml, out, mode);
    if (mode)
        merge_kernel<<<M_TOTAL / 16, 256, 0, stream>>>(Po, Pml, out);
}

// Round 25
// 85.788 us; speedup vs baseline: 1.1136x; 1.1136x over previous
//
#include <hip/hip_runtime.h>
#include <stdint.h>

typedef unsigned short u16;
typedef uint32_t u32;
typedef __bf16 bf16;
typedef bf16 bf16x8 __attribute__((ext_vector_type(8)));
typedef bf16 bf16x4 __attribute__((ext_vector_type(4)));
typedef short s16x4 __attribute__((ext_vector_type(4)));
typedef float f32x4 __attribute__((ext_vector_type(4)));
typedef uint32_t u32x4 __attribute__((ext_vector_type(4)));

// ---- constants: B=4, S=4096, D_IN=768, D_OUT=128 ----
#define S_LEN 4096
#define D_IN 768
#define D_OUT 128
#define NB 4
#define M_TOTAL (NB * S_LEN) // 16384
#define NPROP 115            // proportional-split blocks per batch

// proportional KV-split tables: tile t (of 16, 256 rows) has nj=4t+4 KV tiles and
// SPLITS[t]=ceil(nj/5) splits -> every block runs 4-5 iterations (uniform load).
__device__ const unsigned char SPLITS_T[16] = {1,2,3,4,4,5,6,7,8,8,9,10,11,12,12,13};
__device__ const unsigned char OFF_T[16]    = {0,1,3,6,10,14,19,25,32,40,48,57,67,78,90,102};
__device__ const unsigned char TILE_OF[NPROP] = {
    0, 1,1, 2,2,2, 3,3,3,3, 4,4,4,4, 5,5,5,5,5, 6,6,6,6,6,6, 7,7,7,7,7,7,7,
    8,8,8,8,8,8,8,8, 9,9,9,9,9,9,9,9, 10,10,10,10,10,10,10,10,10,
    11,11,11,11,11,11,11,11,11,11, 12,12,12,12,12,12,12,12,12,12,12,
    13,13,13,13,13,13,13,13,13,13,13,13, 14,14,14,14,14,14,14,14,14,14,14,14,
    15,15,15,15,15,15,15,15,15,15,15,15,15};

static __device__ __forceinline__ u16 f2bf(float f) {
    union { float f; uint32_t u; } c; c.f = f;
    return (u16)((c.u + 0x7FFFu + ((c.u >> 16) & 1u)) >> 16);
}
static __device__ __forceinline__ float bf2f_lo(uint32_t w) { return __uint_as_float(w << 16); }
static __device__ __forceinline__ float bf2f_hi(uint32_t w) { return __uint_as_float(w & 0xFFFF0000u); }

static __device__ __forceinline__ bf16x8 ld8(const u16* p) {
    union { u32x4 v; bf16x8 b; } c;
    c.v = *reinterpret_cast<const u32x4*>(p);
    return c.b;
}

static __device__ __forceinline__ f32x4 mfma16(bf16x8 a, bf16x8 b, f32x4 c) {
    return __builtin_amdgcn_mfma_f32_16x16x32_bf16(a, b, c, 0, 0, 0);
}

// 16x16x16 bf16 MFMA: B-layout == 16x16 D-layout (S^T feeds PV with no cross-lane ops).
// Guard with __HIP_DEVICE_COMPILE__: __has_builtin is false in the host pass (R15).
static __device__ __forceinline__ f32x4 mfma16k16(uint2 a, uint2 b, f32x4 c) {
#if defined(__HIP_DEVICE_COMPILE__)
#if __has_builtin(__builtin_amdgcn_mfma_f32_16x16x16_bf16)
    union { uint2 u; bf16x4 v; } ca, cb; ca.u = a; cb.u = b;
    return __builtin_amdgcn_mfma_f32_16x16x16_bf16(ca.v, cb.v, c, 0, 0, 0);
#else
    union { uint2 u; s16x4 v; } ca, cb; ca.u = a; cb.u = b;
    return __builtin_amdgcn_mfma_f32_16x16x16bf16_1k(ca.v, cb.v, c, 0, 0, 0);
#endif
#else
    (void)a; (void)b;
    return c; // host pass stub -- never executed
#endif
}

// async global->LDS, 16B per lane; dest = uniform base + lane*16 (linear)
static __device__ __forceinline__ void gload16(const void* g, void* l) {
    __builtin_amdgcn_global_load_lds((const __attribute__((address_space(1))) uint32_t*)g,
                                     (__attribute__((address_space(3))) uint32_t*)l, 16, 0, 0);
}

static __device__ __forceinline__ float bpermf(int addr, float v) {
    return __int_as_float(__builtin_amdgcn_ds_bpermute(addr, __float_as_int(v)));
}
// truncating bf16 pack: low16 = bf16(a), high16 = bf16(b), one v_perm_b32
static __device__ __forceinline__ u32 pk2(float a, float b) {
    return __builtin_amdgcn_perm(__float_as_uint(b), __float_as_uint(a), 0x07060302u);
}

// ---------------- Kernel 1: W -> W^T bf16 via LDS transpose ----------------
__global__ __launch_bounds__(256) void wt_kernel(const float* __restrict__ Wq, const float* __restrict__ Wk,
                                                 const float* __restrict__ Wv, u16* __restrict__ Wt) {
    __shared__ u16 tl[128][40];
    const int w = blockIdx.x / 24;
    const int kc = (blockIdx.x % 24) * 32;
    const float* W = (w == 0) ? Wq : (w == 1) ? Wk : Wv;
#pragma unroll
    for (int p = 0; p < 4; ++p) {
        int kr = p * 8 + (threadIdx.x >> 5);
        int nc = (threadIdx.x & 31) * 4;
        float4 v = *reinterpret_cast<const float4*>(W + (size_t)(kc + kr) * D_OUT + nc);
        tl[nc + 0][kr] = f2bf(v.x); tl[nc + 1][kr] = f2bf(v.y);
        tl[nc + 2][kr] = f2bf(v.z); tl[nc + 3][kr] = f2bf(v.w);
    }
    __syncthreads();
    const int n = threadIdx.x >> 1, kh = (threadIdx.x & 1) * 16;
    u32x4* dst = reinterpret_cast<u32x4*>(Wt + (size_t)w * D_OUT * D_IN + (size_t)n * D_IN + kc + kh);
    const u32x4* src = reinterpret_cast<const u32x4*>(&tl[n][kh]);
    dst[0] = src[0];
    dst[1] = src[1];
}

// ---------------- Kernel 2: fused QKV projection, y-split, K-step 64 ----------------
// grid (256,3), block 256 (4 waves x 16 rows); block = 64 rows x 128 cols x ONE of
// Q/K/V (y). 768 blocks = 3 blocks/CU. W[y] staged in LDS dbuf (2x16KB) + x
// bf16-packed dbuf (2x8KB) = 48KB. Single barrier/iter, 16 MFMA/wave/barrier, 12 iters.
// (R24's 6-way split at 8 MFMA/barrier + 6x x-re-read regressed 33->44us; this is
// the measured joint optimum of {blocks/CU, MFMA/barrier}.)
__global__ __launch_bounds__(256) void qkv_kernel(const float* __restrict__ x, const u16* __restrict__ Wt,
                                                  u16* __restrict__ Qb, u16* __restrict__ Kb,
                                                  u16* __restrict__ Vt) {
    __shared__ __align__(16) u16 wslab[2][128 * 64]; // [col][64k] bf16, slot^=(row&7)
    __shared__ __align__(16) u16 xslab[2][64 * 64];  // [row][64k] bf16, slot^=(row&7)
    const int wave = threadIdx.x >> 6, lane = threadIdx.x & 63;
    const int r = lane & 15, g = lane >> 4;
    const int m0 = blockIdx.x * 64;
    const int y = blockIdx.y;
    const u16* wt = Wt + (size_t)y * D_OUT * D_IN;

    f32x4 acc[8];
#pragma unroll
    for (int f = 0; f < 8; ++f) acc[f] = f32x4{0.f, 0.f, 0.f, 0.f};

    // stage W[y][0..128 cols][kk*64..+64]: 16 chunks of 1KB (8 rows x 128B)
    auto stageW = [&](int bb, int kk) {
#pragma unroll
        for (int i = 0; i < 4; ++i) {
            int c = i * 4 + wave;                 // 0..15
            int rr = c * 8 + (lane >> 3);         // W^T row (output col) 0..127
            int slot = (lane & 7) ^ (rr & 7);
            const u16* src = wt + (size_t)rr * D_IN + kk * 64 + slot * 8;
            gload16(src, &wslab[bb][c * 512]);
        }
    };
    auto loadX = [&](int kk, float4* v) {
        const float* src = x + (size_t)(m0 + (threadIdx.x >> 2)) * D_IN + kk * 64 + (threadIdx.x & 3) * 16;
        v[0] = *reinterpret_cast<const float4*>(src);
        v[1] = *reinterpret_cast<const float4*>(src + 4);
        v[2] = *reinterpret_cast<const float4*>(src + 8);
        v[3] = *reinterpret_cast<const float4*>(src + 12);
    };
    auto writeX = [&](int bb, const float4* v) {
        const int row = threadIdx.x >> 2, w2 = (threadIdx.x & 3) * 2;
        u32x4 p0, p1;
        p0[0] = pk2(v[0].x, v[0].y); p0[1] = pk2(v[0].z, v[0].w);
        p0[2] = pk2(v[1].x, v[1].y); p0[3] = pk2(v[1].z, v[1].w);
        p1[0] = pk2(v[2].x, v[2].y); p1[1] = pk2(v[2].z, v[2].w);
        p1[2] = pk2(v[3].x, v[3].y); p1[3] = pk2(v[3].z, v[3].w);
        *reinterpret_cast<u32x4*>(&xslab[bb][row * 64 + ((w2 ^ (row & 7)) * 8)]) = p0;
        *reinterpret_cast<u32x4*>(&xslab[bb][row * 64 + (((w2 + 1) ^ (row & 7)) * 8)]) = p1;
    };

    float4 xv[4];
    stageW(0, 0);
    loadX(0, xv);
    int buf = 0;
    const int arow = wave * 16 + r;
    for (int kk = 0; kk < 12; ++kk) {
        writeX(buf, xv);
        asm volatile("s_waitcnt lgkmcnt(0)" ::: "memory"); // my ds_writes drained
        asm volatile("s_waitcnt vmcnt(0)" ::: "memory");   // W(buf) DMA done (issued last iter)
        __builtin_amdgcn_sched_barrier(0);
        __builtin_amdgcn_s_barrier();                      // all waves: W(buf)+x(buf) visible
        if (kk + 1 < 12) {
            stageW(buf ^ 1, kk + 1);
            loadX(kk + 1, xv);
        }
#pragma unroll
        for (int kk2 = 0; kk2 < 2; ++kk2) {
            bf16x8 xa = ld8(&xslab[buf][arow * 64 + (((kk2 * 4 + g) ^ (arow & 7)) * 8)]);
#pragma unroll
            for (int f = 0; f < 8; ++f) {
                int rr = f * 16 + r;
                bf16x8 wf = ld8(&wslab[buf][rr * 64 + (((kk2 * 4 + g) ^ (rr & 7)) * 8)]);
                acc[f] = mfma16(xa, wf, acc[f]);
            }
        }
        buf ^= 1;
    }
    asm volatile("s_waitcnt vmcnt(0)" ::: "memory"); // retire-safety (R7 lesson)

    const float QSC = 0.1275174366f; // log2(e)/sqrt(128) folded into Q
    if (y == 0) {
#pragma unroll
        for (int f = 0; f < 8; ++f)
#pragma unroll
            for (int i = 0; i < 4; ++i) {
                int mrow = m0 + wave * 16 + 4 * g + i;
                Qb[(size_t)mrow * D_OUT + f * 16 + r] = f2bf(acc[f][i] * QSC);
            }
    } else if (y == 1) {
#pragma unroll
        for (int f = 0; f < 8; ++f)
#pragma unroll
            for (int i = 0; i < 4; ++i) {
                int mrow = m0 + wave * 16 + 4 * g + i;
                Kb[(size_t)mrow * D_OUT + f * 16 + r] = f2bf(acc[f][i]);
            }
    } else {
#pragma unroll
        for (int f = 0; f < 8; ++f)
#pragma unroll
            for (int i = 0; i < 4; ++i) {
                int mrow = m0 + wave * 16 + 4 * g + i;
                Vt[((size_t)((mrow >> 12) * D_OUT + f * 16 + r)) * S_LEN + (mrow & 4095)] = f2bf(acc[f][i]);
            }
    }
}

// ---------------- Kernel 3: causal flash attention (proportional KV-split, XCD-affine) ----------------
// mode=1: grid 464; b=(n>>1)&3 (XCD affinity), idx=(n>>3)*2+(n&1) selects (t,s).
// mode=0 (ws fallback): grid 64, direct out.
__global__ __launch_bounds__(512, 2) void attn_kernel(const u16* __restrict__ Qb, const u16* __restrict__ Kb,
                                                      const u16* __restrict__ Vt, u16* __restrict__ Po,
                                                      float* __restrict__ Pml, float* __restrict__ out,
                                                      int mode) {
    __shared__ __align__(16) u16 kbuf[2][64 * 128]; // [key][128d], slot^=(row&7)
    __shared__ __align__(16) u16 vbuf[2][128 * 64]; // [d][64key], slot^=(row&7)

    const int wave = threadIdx.x >> 6, lane = threadIdx.x & 63;
    const int r = lane & 15, g = lane >> 4;
    const int n = (int)blockIdx.x;
    int b, t, s, sp, pt;
    if (mode) {
        b = (n >> 1) & 3;                          // XCD batch affinity
        const int idx = (n >> 3) * 2 + (n & 1);
        if (idx >= NPROP) return;
        t = TILE_OF[idx];
        s = idx - OFF_T[t];
        sp = SPLITS_T[t];
        pt = b * NPROP + idx;
    } else {
        b = n >> 4; t = n & 15; s = 0; sp = 1; pt = 0;
    }
    const int nj = 4 * t + 4;
    const int qw0 = t * 256 + wave * 32;

    const u16* Kp = Kb + (size_t)b * S_LEN * D_OUT;
    const u16* Vp = Vt + (size_t)b * D_OUT * S_LEN;

    // Q as B-fragments (col=query on lane&15, k=d)
    bf16x8 qf[2][4];
#pragma unroll
    for (int rb = 0; rb < 2; ++rb)
#pragma unroll
        for (int kk = 0; kk < 4; ++kk)
            qf[rb][kk] = ld8(Qb + ((size_t)(b * S_LEN + qw0 + rb * 16 + r)) * D_OUT + kk * 32 + 8 * g);

    f32x4 o[2][8]; // o[rb][f][i] = O~^T[d=16f+4g+i][q=qw0+rb*16+r]
    float l_[2];
#pragma unroll
    for (int rb = 0; rb < 2; ++rb) {
#pragma unroll
        for (int f = 0; f < 8; ++f) o[rb][f] = f32x4{0.f, 0.f, 0.f, 0.f};
        l_[rb] = 0.f;
    }

    const int lx16 = (lane ^ 16) * 4, lx32 = (lane ^ 32) * 4;

    auto stageK = [&](int bb, int k0) {
#pragma unroll
        for (int i = 0; i < 2; ++i) {
            int c = i * 8 + wave;                 // 0..15, 1KB chunks (4 key-rows)
            int row = c * 4 + (lane >> 4);
            const u16* src = Kp + (size_t)(k0 + row) * D_OUT + (((lane & 15) ^ (row & 7)) * 8);
            gload16(src, &kbuf[bb][c * 512]);
        }
    };
    auto stageV = [&](int bb, int k0) {
#pragma unroll
        for (int i = 0; i < 2; ++i) {
            int c = i * 8 + wave;                 // 0..15, 1KB chunks (8 d-rows)
            int row = c * 8 + (lane >> 3);
            const u16* src = Vp + (size_t)row * S_LEN + k0 + (((lane & 7) ^ (row & 7)) * 8);
            gload16(src, &vbuf[bb][c * 512]);
        }
    };

    stageK(0, s * 64);
    stageV(0, s * 64);
    int buf = 0;
    for (int j = s; j < nj; j += sp) {
        const int k0 = j * 64;
        asm volatile("s_waitcnt vmcnt(0)" ::: "memory"); // stage(buf) done (issued a full iter ago)
        __builtin_amdgcn_sched_barrier(0);
        __builtin_amdgcn_s_barrier();                    // all waves done reading buf^1
        const int j2 = j + sp;
        if (j2 < nj) {                                   // stage next tile into buf^1
            stageK(buf ^ 1, j2 * 64);
            stageV(buf ^ 1, j2 * 64);
        }

        // ---- S^T = K Q : thread holds S^T[key=k0+16f+4g+i][q=qw0+rb*16+r] ----
        f32x4 sv[2][4];
#pragma unroll
        for (int rb = 0; rb < 2; ++rb)
#pragma unroll
            for (int f = 0; f < 4; ++f) sv[rb][f] = f32x4{0.f, 0.f, 0.f, 0.f};
        __builtin_amdgcn_s_setprio(1);
#pragma unroll
        for (int kk = 0; kk < 4; ++kk)
#pragma unroll
            for (int f = 0; f < 4; ++f) {
                bf16x8 kf = ld8(&kbuf[buf][(f * 16 + r) * 128 + (((kk * 4 + g) ^ (r & 7)) * 8)]);
                sv[0][f] = mfma16(kf, qf[0][kk], sv[0][f]);
                sv[1][f] = mfma16(kf, qf[1][kk], sv[1][f]);
            }
        __builtin_amdgcn_s_setprio(0);

        // ---- fixed-base softmax: P = exp2(S); l accumulates per-lane; pack B-frags ----
        uint2 pb[2][4];
#pragma unroll
        for (int rb = 0; rb < 2; ++rb) {
            const int qrb = qw0 + rb * 16;
            const int q = qrb + r;
            if (k0 + 63 > qrb) {
#pragma unroll
                for (int f = 0; f < 4; ++f)
#pragma unroll
                    for (int i = 0; i < 4; ++i)
                        if (k0 + 16 * f + 4 * g + i > q) sv[rb][f][i] = -1e30f; // exp2 -> 0
            }
            float r0 = 0.f;
#pragma unroll
            for (int f = 0; f < 4; ++f)
#pragma unroll
                for (int i = 0; i < 4; ++i) {
                    float p = __builtin_amdgcn_exp2f(sv[rb][f][i]);
                    sv[rb][f][i] = p;
                    r0 += p;
                }
            l_[rb] += r0;
#pragma unroll
            for (int kb = 0; kb < 4; ++kb) {
                pb[rb][kb].x = pk2(sv[rb][kb][0], sv[rb][kb][1]);
                pb[rb][kb].y = pk2(sv[rb][kb][2], sv[rb][kb][3]);
            }
        }

        // ---- O~^T += V^T P^T via 16x16x16 MFMA (A = V^T 4-key slice, B = pb) ----
        __builtin_amdgcn_s_setprio(1);
#pragma unroll
        for (int kb = 0; kb < 4; ++kb) {
            const int vs = ((2 * kb + (g >> 1)) ^ (r & 7)) * 8 + 4 * (g & 1);
#pragma unroll
            for (int f = 0; f < 8; ++f) {
                uint2 vf = *reinterpret_cast<const uint2*>(&vbuf[buf][(f * 16 + r) * 64 + vs]);
                o[0][f] = mfma16k16(vf, pb[0][kb], o[0][f]);
                o[1][f] = mfma16k16(vf, pb[1][kb], o[1][f]);
            }
        }
        __builtin_amdgcn_s_setprio(0);
        buf ^= 1;
    }
    asm volatile("s_waitcnt vmcnt(0)" ::: "memory"); // retire-safety (R7 lesson)

    // finalize l: reduce per-lane partials across the 4 g-groups (once)
    l_[0] += bpermf(lx16, l_[0]);
    l_[1] += bpermf(lx16, l_[1]);
    l_[0] += bpermf(lx32, l_[0]);
    l_[1] += bpermf(lx32, l_[1]);

    if (!mode) {
#pragma unroll
        for (int rb = 0; rb < 2; ++rb) {
            float inv = 1.0f / l_[rb];
            float* orow = out + ((size_t)(b * S_LEN + qw0 + rb * 16 + r)) * D_OUT;
#pragma unroll
            for (int f = 0; f < 8; ++f) {
                float4 v;
                v.x = o[rb][f][0] * inv; v.y = o[rb][f][1] * inv;
                v.z = o[rb][f][2] * inv; v.w = o[rb][f][3] * inv;
                *reinterpret_cast<float4*>(orow + 16 * f + 4 * g) = v;
            }
        }
    } else {
        // wave-coalesced partial layout: chunk (wave,rb,f) = 512B, lane -> base + lane*8B
        u16* po = Po + (size_t)pt * (256 * 128);
        float* pml = Pml + (size_t)pt * 512;
#pragma unroll
        for (int rb = 0; rb < 2; ++rb) {
            u16* chunk0 = po + (size_t)((wave * 2 + rb) * 8) * 256 + lane * 4;
#pragma unroll
            for (int f = 0; f < 8; ++f) {
                u32 w0 = (u32)f2bf(o[rb][f][0]) | ((u32)f2bf(o[rb][f][1]) << 16);
                u32 w1 = (u32)f2bf(o[rb][f][2]) | ((u32)f2bf(o[rb][f][3]) << 16);
                uint2 ww; ww.x = w0; ww.y = w1;
                *reinterpret_cast<uint2*>(chunk0 + f * 256) = ww;
            }
            if (g == 0) {
                const int row = wave * 32 + rb * 16 + r;
                pml[row * 2 + 0] = 0.f;       // unused (fixed base)
                pml[row * 2 + 1] = l_[rb];
            }
        }
    }
}

// ---------------- Kernel 4: split merge (proportional splits, plain sums) ----------------
__global__ __launch_bounds__(256) void merge_kernel(const u16* __restrict__ Po, const float* __restrict__ Pml,
                                                    float* __restrict__ out) {
    const int gr = blockIdx.x * 16 + (threadIdx.x >> 4);
    const int c0 = (threadIdx.x & 15) * 8;
    const int b = gr >> 12, rr = gr & 4095;
    const int t = rr >> 8, row = rr & 255;
    const int ns = SPLITS_T[t];
    const size_t pbase = (size_t)b * NPROP + OFF_T[t];

    // decode (row, c0) -> chunk coords of the attn epilogue layout
    const int wv = row >> 5, rbm = (row >> 4) & 1, r_ = row & 15;
    const int fm = c0 >> 4, g0 = (c0 >> 2) & 3; // g0 in {0,2}
    const size_t coff = (size_t)((wv * 2 + rbm) * 8 + fm) * 256;

    float L = 0.f;
    for (int s = 0; s < ns; ++s) L += Pml[(pbase + s) * 512 + row * 2 + 1];
    const float inv = 1.0f / L;

    float acc[8];
#pragma unroll
    for (int k = 0; k < 8; ++k) acc[k] = 0.f;
    for (int s = 0; s < ns; ++s) {
        const u16* chunk = Po + (pbase + s) * (256 * 128) + coff;
        uint2 pv0 = *reinterpret_cast<const uint2*>(chunk + (g0 * 16 + r_) * 4);
        uint2 pv1 = *reinterpret_cast<const uint2*>(chunk + ((g0 + 1) * 16 + r_) * 4);
        acc[0] += bf2f_lo(pv0.x); acc[1] += bf2f_hi(pv0.x);
        acc[2] += bf2f_lo(pv0.y); acc[3] += bf2f_hi(pv0.y);
        acc[4] += bf2f_lo(pv1.x); acc[5] += bf2f_hi(pv1.x);
        acc[6] += bf2f_lo(pv1.y); acc[7] += bf2f_hi(pv1.y);
    }
    float* op = out + (size_t)gr * D_OUT + c0;
    float4 v0, v1;
    v0.x = acc[0] * inv; v0.y = acc[1] * inv; v0.z = acc[2] * inv; v0.w = acc[3] * inv;
    v1.x = acc[4] * inv; v1.y = acc[5] * inv; v1.z = acc[6] * inv; v1.w = acc[7] * inv;
    *reinterpret_cast<float4*>(op) = v0;
    *reinterpret_cast<float4*>(op + 4) = v1;
}

extern "C" void kernel_launch(void* const* d_in, const int* in_sizes, int n_in,
                              void* d_out, int out_size, void* d_ws, size_t ws_size,
                              hipStream_t stream) {
    const float* x  = (const float*)d_in[0];
    const float* Wq = (const float*)d_in[1];
    const float* Wk = (const float*)d_in[2];
    const float* Wv = (const float*)d_in[3];
    float* out = (float*)d_out;

    // ws layout (u16): Q | K | V^T | W^T | Po | Pml
    u16* Qb = (u16*)d_ws;
    u16* Kb = Qb + (size_t)M_TOTAL * D_OUT;
    u16* Vt = Kb + (size_t)M_TOTAL * D_OUT;
    u16* Wt = Vt + (size_t)M_TOTAL * D_OUT;

    const unsigned long long base = (3ULL * M_TOTAL * D_OUT + 3ULL * D_OUT * D_IN) * 2ULL;
    const unsigned long long perP = 256ULL * 128 * 2 + 512ULL * 4; // Po (64KB) + Pml (2KB)
    const int nblk = NPROP * NB; // 460 partial slots
    const int mode = (ws_size >= base + (unsigned long long)nblk * perP) ? 1 : 0;

    u16* Po = Wt + (size_t)3 * D_OUT * D_IN;
    float* Pml = (float*)(Po + (size_t)nblk * (256 * 128));

    wt_kernel<<<72, 256, 0, stream>>>(Wq, Wk, Wv, Wt);
    qkv_kernel<<<dim3(256, 3), 256, 0, stream>>>(x, Wt, Qb, Kb, Vt);
    attn_kernel<<<mode ? 464 : 16 * NB, 512, 0, stream>>>(Qb, Kb, Vt, Po, Pml, out, mode);
    if (mode)
        merge_kernel<<<M_TOTAL / 16, 256, 0, stream>>>(Po, Pml, out);
}

// Round 26
// 85.423 us; speedup vs baseline: 1.1184x; 1.0043x over previous
//
#include <hip/hip_runtime.h>
#include <stdint.h>

typedef unsigned short u16;
typedef uint32_t u32;
typedef __bf16 bf16;
typedef bf16 bf16x8 __attribute__((ext_vector_type(8)));
typedef bf16 bf16x4 __attribute__((ext_vector_type(4)));
typedef short s16x4 __attribute__((ext_vector_type(4)));
typedef float f32x4 __attribute__((ext_vector_type(4)));
typedef uint32_t u32x4 __attribute__((ext_vector_type(4)));

// ---- constants: B=4, S=4096, D_IN=768, D_OUT=128 ----
#define S_LEN 4096
#define D_IN 768
#define D_OUT 128
#define NB 4
#define M_TOTAL (NB * S_LEN) // 16384
#define NPROP 115            // proportional-split blocks per batch

// proportional KV-split tables: tile t (of 16, 256 rows) has nj=4t+4 KV tiles and
// SPLITS[t]=ceil(nj/5) splits -> every block runs 4-5 iterations (uniform load).
__device__ const unsigned char SPLITS_T[16] = {1,2,3,4,4,5,6,7,8,8,9,10,11,12,12,13};
__device__ const unsigned char OFF_T[16]    = {0,1,3,6,10,14,19,25,32,40,48,57,67,78,90,102};
__device__ const unsigned char TILE_OF[NPROP] = {
    0, 1,1, 2,2,2, 3,3,3,3, 4,4,4,4, 5,5,5,5,5, 6,6,6,6,6,6, 7,7,7,7,7,7,7,
    8,8,8,8,8,8,8,8, 9,9,9,9,9,9,9,9, 10,10,10,10,10,10,10,10,10,
    11,11,11,11,11,11,11,11,11,11, 12,12,12,12,12,12,12,12,12,12,12,
    13,13,13,13,13,13,13,13,13,13,13,13, 14,14,14,14,14,14,14,14,14,14,14,14,
    15,15,15,15,15,15,15,15,15,15,15,15,15};

static __device__ __forceinline__ u16 f2bf(float f) {
    union { float f; uint32_t u; } c; c.f = f;
    return (u16)((c.u + 0x7FFFu + ((c.u >> 16) & 1u)) >> 16);
}
static __device__ __forceinline__ float bf2f_lo(uint32_t w) { return __uint_as_float(w << 16); }
static __device__ __forceinline__ float bf2f_hi(uint32_t w) { return __uint_as_float(w & 0xFFFF0000u); }

static __device__ __forceinline__ bf16x8 ld8(const u16* p) {
    union { u32x4 v; bf16x8 b; } c;
    c.v = *reinterpret_cast<const u32x4*>(p);
    return c.b;
}

static __device__ __forceinline__ f32x4 mfma16(bf16x8 a, bf16x8 b, f32x4 c) {
    return __builtin_amdgcn_mfma_f32_16x16x32_bf16(a, b, c, 0, 0, 0);
}

// 16x16x16 bf16 MFMA: B-layout == 16x16 D-layout (S^T feeds PV with no cross-lane ops).
// Guard with __HIP_DEVICE_COMPILE__: __has_builtin is false in the host pass (R15).
static __device__ __forceinline__ f32x4 mfma16k16(uint2 a, uint2 b, f32x4 c) {
#if defined(__HIP_DEVICE_COMPILE__)
#if __has_builtin(__builtin_amdgcn_mfma_f32_16x16x16_bf16)
    union { uint2 u; bf16x4 v; } ca, cb; ca.u = a; cb.u = b;
    return __builtin_amdgcn_mfma_f32_16x16x16_bf16(ca.v, cb.v, c, 0, 0, 0);
#else
    union { uint2 u; s16x4 v; } ca, cb; ca.u = a; cb.u = b;
    return __builtin_amdgcn_mfma_f32_16x16x16bf16_1k(ca.v, cb.v, c, 0, 0, 0);
#endif
#else
    (void)a; (void)b;
    return c; // host pass stub -- never executed
#endif
}

// async global->LDS, 16B per lane; dest = uniform base + lane*16 (linear)
static __device__ __forceinline__ void gload16(const void* g, void* l) {
    __builtin_amdgcn_global_load_lds((const __attribute__((address_space(1))) uint32_t*)g,
                                     (__attribute__((address_space(3))) uint32_t*)l, 16, 0, 0);
}

static __device__ __forceinline__ float bpermf(int addr, float v) {
    return __int_as_float(__builtin_amdgcn_ds_bpermute(addr, __float_as_int(v)));
}
// truncating bf16 pack: low16 = bf16(a), high16 = bf16(b), one v_perm_b32
static __device__ __forceinline__ u32 pk2(float a, float b) {
    return __builtin_amdgcn_perm(__float_as_uint(b), __float_as_uint(a), 0x07060302u);
}

// ---------------- Kernel 1: W -> W^T bf16 via LDS transpose ----------------
__global__ __launch_bounds__(256) void wt_kernel(const float* __restrict__ Wq, const float* __restrict__ Wk,
                                                 const float* __restrict__ Wv, u16* __restrict__ Wt) {
    __shared__ u16 tl[128][40];
    const int w = blockIdx.x / 24;
    const int kc = (blockIdx.x % 24) * 32;
    const float* W = (w == 0) ? Wq : (w == 1) ? Wk : Wv;
#pragma unroll
    for (int p = 0; p < 4; ++p) {
        int kr = p * 8 + (threadIdx.x >> 5);
        int nc = (threadIdx.x & 31) * 4;
        float4 v = *reinterpret_cast<const float4*>(W + (size_t)(kc + kr) * D_OUT + nc);
        tl[nc + 0][kr] = f2bf(v.x); tl[nc + 1][kr] = f2bf(v.y);
        tl[nc + 2][kr] = f2bf(v.z); tl[nc + 3][kr] = f2bf(v.w);
    }
    __syncthreads();
    const int n = threadIdx.x >> 1, kh = (threadIdx.x & 1) * 16;
    u32x4* dst = reinterpret_cast<u32x4*>(Wt + (size_t)w * D_OUT * D_IN + (size_t)n * D_IN + kc + kh);
    const u32x4* src = reinterpret_cast<const u32x4*>(&tl[n][kh]);
    dst[0] = src[0];
    dst[1] = src[1];
}

// ---------------- Kernel 2: fused QKV projection, M-tile 128, y-split ----------------
// grid (128,3), block 512 (8 waves x 16 rows); block = 128 rows x 128 cols x ONE of
// Q/K/V (y). Halves the W LDS-DMA traffic vs R23's 64-row blocks (147->74MB; W is
// re-staged once per block) while RAISING waves/CU 12->16 (2 blocks x 8 waves at
// exactly 64KB LDS). W dbuf 2x16KB + x bf16-packed dbuf 2x16KB. Single barrier/iter,
// 16 MFMA/wave/barrier (R23/R24-validated floor), 12 iters.
__global__ __launch_bounds__(512) void qkv_kernel(const float* __restrict__ x, const u16* __restrict__ Wt,
                                                  u16* __restrict__ Qb, u16* __restrict__ Kb,
                                                  u16* __restrict__ Vt) {
    __shared__ __align__(16) u16 wslab[2][128 * 64]; // [col][64k] bf16, slot^=(row&7)
    __shared__ __align__(16) u16 xslab[2][128 * 64]; // [row][64k] bf16, slot^=(row&7)
    const int wave = threadIdx.x >> 6, lane = threadIdx.x & 63;
    const int r = lane & 15, g = lane >> 4;
    const int m0 = blockIdx.x * 128;
    const int y = blockIdx.y;
    const u16* wt = Wt + (size_t)y * D_OUT * D_IN;

    f32x4 acc[8];
#pragma unroll
    for (int f = 0; f < 8; ++f) acc[f] = f32x4{0.f, 0.f, 0.f, 0.f};

    // stage W[y][0..128 cols][kk*64..+64]: 16 chunks of 1KB (8 rows x 128B), 2/wave
    auto stageW = [&](int bb, int kk) {
#pragma unroll
        for (int i = 0; i < 2; ++i) {
            int c = wave * 2 + i;                 // 0..15
            int rr = c * 8 + (lane >> 3);         // W^T row (output col) 0..127
            int slot = (lane & 7) ^ (rr & 7);
            const u16* src = wt + (size_t)rr * D_IN + kk * 64 + slot * 8;
            gload16(src, &wslab[bb][c * 512]);
        }
    };
    // x: thread loads 16 floats of row (tid>>2) (0..127), k-part (tid&3)*16
    auto loadX = [&](int kk, float4* v) {
        const float* src = x + (size_t)(m0 + (threadIdx.x >> 2)) * D_IN + kk * 64 + (threadIdx.x & 3) * 16;
        v[0] = *reinterpret_cast<const float4*>(src);
        v[1] = *reinterpret_cast<const float4*>(src + 4);
        v[2] = *reinterpret_cast<const float4*>(src + 8);
        v[3] = *reinterpret_cast<const float4*>(src + 12);
    };
    auto writeX = [&](int bb, const float4* v) {
        const int row = threadIdx.x >> 2, w2 = (threadIdx.x & 3) * 2;
        u32x4 p0, p1;
        p0[0] = pk2(v[0].x, v[0].y); p0[1] = pk2(v[0].z, v[0].w);
        p0[2] = pk2(v[1].x, v[1].y); p0[3] = pk2(v[1].z, v[1].w);
        p1[0] = pk2(v[2].x, v[2].y); p1[1] = pk2(v[2].z, v[2].w);
        p1[2] = pk2(v[3].x, v[3].y); p1[3] = pk2(v[3].z, v[3].w);
        *reinterpret_cast<u32x4*>(&xslab[bb][row * 64 + ((w2 ^ (row & 7)) * 8)]) = p0;
        *reinterpret_cast<u32x4*>(&xslab[bb][row * 64 + (((w2 + 1) ^ (row & 7)) * 8)]) = p1;
    };

    float4 xv[4];
    stageW(0, 0);
    loadX(0, xv);
    int buf = 0;
    const int arow = wave * 16 + r;               // 0..127
    for (int kk = 0; kk < 12; ++kk) {
        writeX(buf, xv);
        asm volatile("s_waitcnt lgkmcnt(0)" ::: "memory"); // my ds_writes drained
        asm volatile("s_waitcnt vmcnt(0)" ::: "memory");   // W(buf) DMA done (issued last iter)
        __builtin_amdgcn_sched_barrier(0);
        __builtin_amdgcn_s_barrier();                      // all waves: W(buf)+x(buf) visible
        if (kk + 1 < 12) {
            stageW(buf ^ 1, kk + 1);
            loadX(kk + 1, xv);
        }
#pragma unroll
        for (int kk2 = 0; kk2 < 2; ++kk2) {
            bf16x8 xa = ld8(&xslab[buf][arow * 64 + (((kk2 * 4 + g) ^ (arow & 7)) * 8)]);
#pragma unroll
            for (int f = 0; f < 8; ++f) {
                int rr = f * 16 + r;
                bf16x8 wf = ld8(&wslab[buf][rr * 64 + (((kk2 * 4 + g) ^ (rr & 7)) * 8)]);
                acc[f] = mfma16(xa, wf, acc[f]);
            }
        }
        buf ^= 1;
    }
    asm volatile("s_waitcnt vmcnt(0)" ::: "memory"); // retire-safety (R7 lesson)

    const float QSC = 0.1275174366f; // log2(e)/sqrt(128) folded into Q
    if (y == 0) {
#pragma unroll
        for (int f = 0; f < 8; ++f)
#pragma unroll
            for (int i = 0; i < 4; ++i) {
                int mrow = m0 + wave * 16 + 4 * g + i;
                Qb[(size_t)mrow * D_OUT + f * 16 + r] = f2bf(acc[f][i] * QSC);
            }
    } else if (y == 1) {
#pragma unroll
        for (int f = 0; f < 8; ++f)
#pragma unroll
            for (int i = 0; i < 4; ++i) {
                int mrow = m0 + wave * 16 + 4 * g + i;
                Kb[(size_t)mrow * D_OUT + f * 16 + r] = f2bf(acc[f][i]);
            }
    } else {
#pragma unroll
        for (int f = 0; f < 8; ++f)
#pragma unroll
            for (int i = 0; i < 4; ++i) {
                int mrow = m0 + wave * 16 + 4 * g + i;
                Vt[((size_t)((mrow >> 12) * D_OUT + f * 16 + r)) * S_LEN + (mrow & 4095)] = f2bf(acc[f][i]);
            }
    }
}

// ---------------- Kernel 3: causal flash attention (proportional KV-split, XCD-affine) ----------------
// mode=1: grid 464; b=(n>>1)&3 (XCD affinity), idx=(n>>3)*2+(n&1) selects (t,s).
// mode=0 (ws fallback): grid 64, direct out.
__global__ __launch_bounds__(512, 2) void attn_kernel(const u16* __restrict__ Qb, const u16* __restrict__ Kb,
                                                      const u16* __restrict__ Vt, u16* __restrict__ Po,
                                                      float* __restrict__ Pml, float* __restrict__ out,
                                                      int mode) {
    __shared__ __align__(16) u16 kbuf[2][64 * 128]; // [key][128d], slot^=(row&7)
    __shared__ __align__(16) u16 vbuf[2][128 * 64]; // [d][64key], slot^=(row&7)

    const int wave = threadIdx.x >> 6, lane = threadIdx.x & 63;
    const int r = lane & 15, g = lane >> 4;
    const int n = (int)blockIdx.x;
    int b, t, s, sp, pt;
    if (mode) {
        b = (n >> 1) & 3;                          // XCD batch affinity
        const int idx = (n >> 3) * 2 + (n & 1);
        if (idx >= NPROP) return;
        t = TILE_OF[idx];
        s = idx - OFF_T[t];
        sp = SPLITS_T[t];
        pt = b * NPROP + idx;
    } else {
        b = n >> 4; t = n & 15; s = 0; sp = 1; pt = 0;
    }
    const int nj = 4 * t + 4;
    const int qw0 = t * 256 + wave * 32;

    const u16* Kp = Kb + (size_t)b * S_LEN * D_OUT;
    const u16* Vp = Vt + (size_t)b * D_OUT * S_LEN;

    // Q as B-fragments (col=query on lane&15, k=d)
    bf16x8 qf[2][4];
#pragma unroll
    for (int rb = 0; rb < 2; ++rb)
#pragma unroll
        for (int kk = 0; kk < 4; ++kk)
            qf[rb][kk] = ld8(Qb + ((size_t)(b * S_LEN + qw0 + rb * 16 + r)) * D_OUT + kk * 32 + 8 * g);

    f32x4 o[2][8]; // o[rb][f][i] = O~^T[d=16f+4g+i][q=qw0+rb*16+r]
    float l_[2];
#pragma unroll
    for (int rb = 0; rb < 2; ++rb) {
#pragma unroll
        for (int f = 0; f < 8; ++f) o[rb][f] = f32x4{0.f, 0.f, 0.f, 0.f};
        l_[rb] = 0.f;
    }

    const int lx16 = (lane ^ 16) * 4, lx32 = (lane ^ 32) * 4;

    auto stageK = [&](int bb, int k0) {
#pragma unroll
        for (int i = 0; i < 2; ++i) {
            int c = i * 8 + wave;                 // 0..15, 1KB chunks (4 key-rows)
            int row = c * 4 + (lane >> 4);
            const u16* src = Kp + (size_t)(k0 + row) * D_OUT + (((lane & 15) ^ (row & 7)) * 8);
            gload16(src, &kbuf[bb][c * 512]);
        }
    };
    auto stageV = [&](int bb, int k0) {
#pragma unroll
        for (int i = 0; i < 2; ++i) {
            int c = i * 8 + wave;                 // 0..15, 1KB chunks (8 d-rows)
            int row = c * 8 + (lane >> 3);
            const u16* src = Vp + (size_t)row * S_LEN + k0 + (((lane & 7) ^ (row & 7)) * 8);
            gload16(src, &vbuf[bb][c * 512]);
        }
    };

    stageK(0, s * 64);
    stageV(0, s * 64);
    int buf = 0;
    for (int j = s; j < nj; j += sp) {
        const int k0 = j * 64;
        asm volatile("s_waitcnt vmcnt(0)" ::: "memory"); // stage(buf) done (issued a full iter ago)
        __builtin_amdgcn_sched_barrier(0);
        __builtin_amdgcn_s_barrier();                    // all waves done reading buf^1
        const int j2 = j + sp;
        if (j2 < nj) {                                   // stage next tile into buf^1
            stageK(buf ^ 1, j2 * 64);
            stageV(buf ^ 1, j2 * 64);
        }

        // ---- S^T = K Q : thread holds S^T[key=k0+16f+4g+i][q=qw0+rb*16+r] ----
        f32x4 sv[2][4];
#pragma unroll
        for (int rb = 0; rb < 2; ++rb)
#pragma unroll
            for (int f = 0; f < 4; ++f) sv[rb][f] = f32x4{0.f, 0.f, 0.f, 0.f};
        __builtin_amdgcn_s_setprio(1);
#pragma unroll
        for (int kk = 0; kk < 4; ++kk)
#pragma unroll
            for (int f = 0; f < 4; ++f) {
                bf16x8 kf = ld8(&kbuf[buf][(f * 16 + r) * 128 + (((kk * 4 + g) ^ (r & 7)) * 8)]);
                sv[0][f] = mfma16(kf, qf[0][kk], sv[0][f]);
                sv[1][f] = mfma16(kf, qf[1][kk], sv[1][f]);
            }
        __builtin_amdgcn_s_setprio(0);

        // ---- fixed-base softmax: P = exp2(S); l accumulates per-lane; pack B-frags ----
        uint2 pb[2][4];
#pragma unroll
        for (int rb = 0; rb < 2; ++rb) {
            const int qrb = qw0 + rb * 16;
            const int q = qrb + r;
            if (k0 + 63 > qrb) {
#pragma unroll
                for (int f = 0; f < 4; ++f)
#pragma unroll
                    for (int i = 0; i < 4; ++i)
                        if (k0 + 16 * f + 4 * g + i > q) sv[rb][f][i] = -1e30f; // exp2 -> 0
            }
            float r0 = 0.f;
#pragma unroll
            for (int f = 0; f < 4; ++f)
#pragma unroll
                for (int i = 0; i < 4; ++i) {
                    float p = __builtin_amdgcn_exp2f(sv[rb][f][i]);
                    sv[rb][f][i] = p;
                    r0 += p;
                }
            l_[rb] += r0;
#pragma unroll
            for (int kb = 0; kb < 4; ++kb) {
                pb[rb][kb].x = pk2(sv[rb][kb][0], sv[rb][kb][1]);
                pb[rb][kb].y = pk2(sv[rb][kb][2], sv[rb][kb][3]);
            }
        }

        // ---- O~^T += V^T P^T via 16x16x16 MFMA (A = V^T 4-key slice, B = pb) ----
        __builtin_amdgcn_s_setprio(1);
#pragma unroll
        for (int kb = 0; kb < 4; ++kb) {
            const int vs = ((2 * kb + (g >> 1)) ^ (r & 7)) * 8 + 4 * (g & 1);
#pragma unroll
            for (int f = 0; f < 8; ++f) {
                uint2 vf = *reinterpret_cast<const uint2*>(&vbuf[buf][(f * 16 + r) * 64 + vs]);
                o[0][f] = mfma16k16(vf, pb[0][kb], o[0][f]);
                o[1][f] = mfma16k16(vf, pb[1][kb], o[1][f]);
            }
        }
        __builtin_amdgcn_s_setprio(0);
        buf ^= 1;
    }
    asm volatile("s_waitcnt vmcnt(0)" ::: "memory"); // retire-safety (R7 lesson)

    // finalize l: reduce per-lane partials across the 4 g-groups (once)
    l_[0] += bpermf(lx16, l_[0]);
    l_[1] += bpermf(lx16, l_[1]);
    l_[0] += bpermf(lx32, l_[0]);
    l_[1] += bpermf(lx32, l_[1]);

    if (!mode) {
#pragma unroll
        for (int rb = 0; rb < 2; ++rb) {
            float inv = 1.0f / l_[rb];
            float* orow = out + ((size_t)(b * S_LEN + qw0 + rb * 16 + r)) * D_OUT;
#pragma unroll
            for (int f = 0; f < 8; ++f) {
                float4 v;
                v.x = o[rb][f][0] * inv; v.y = o[rb][f][1] * inv;
                v.z = o[rb][f][2] * inv; v.w = o[rb][f][3] * inv;
                *reinterpret_cast<float4*>(orow + 16 * f + 4 * g) = v;
            }
        }
    } else {
        // wave-coalesced partial layout: chunk (wave,rb,f) = 512B, lane -> base + lane*8B
        u16* po = Po + (size_t)pt * (256 * 128);
        float* pml = Pml + (size_t)pt * 512;
#pragma unroll
        for (int rb = 0; rb < 2; ++rb) {
            u16* chunk0 = po + (size_t)((wave * 2 + rb) * 8) * 256 + lane * 4;
#pragma unroll
            for (int f = 0; f < 8; ++f) {
                u32 w0 = (u32)f2bf(o[rb][f][0]) | ((u32)f2bf(o[rb][f][1]) << 16);
                u32 w1 = (u32)f2bf(o[rb][f][2]) | ((u32)f2bf(o[rb][f][3]) << 16);
                uint2 ww; ww.x = w0; ww.y = w1;
                *reinterpret_cast<uint2*>(chunk0 + f * 256) = ww;
            }
            if (g == 0) {
                const int row = wave * 32 + rb * 16 + r;
                pml[row * 2 + 0] = 0.f;       // unused (fixed base)
                pml[row * 2 + 1] = l_[rb];
            }
        }
    }
}

// ---------------- Kernel 4: split merge (proportional splits, plain sums) ----------------
__global__ __launch_bounds__(256) void merge_kernel(const u16* __restrict__ Po, const float* __restrict__ Pml,
                                                    float* __restrict__ out) {
    const int gr = blockIdx.x * 16 + (threadIdx.x >> 4);
    const int c0 = (threadIdx.x & 15) * 8;
    const int b = gr >> 12, rr = gr & 4095;
    const int t = rr >> 8, row = rr & 255;
    const int ns = SPLITS_T[t];
    const size_t pbase = (size_t)b * NPROP + OFF_T[t];

    // decode (row, c0) -> chunk coords of the attn epilogue layout
    const int wv = row >> 5, rbm = (row >> 4) & 1, r_ = row & 15;
    const int fm = c0 >> 4, g0 = (c0 >> 2) & 3; // g0 in {0,2}
    const size_t coff = (size_t)((wv * 2 + rbm) * 8 + fm) * 256;

    float L = 0.f;
    for (int s = 0; s < ns; ++s) L += Pml[(pbase + s) * 512 + row * 2 + 1];
    const float inv = 1.0f / L;

    float acc[8];
#pragma unroll
    for (int k = 0; k < 8; ++k) acc[k] = 0.f;
    for (int s = 0; s < ns; ++s) {
        const u16* chunk = Po + (pbase + s) * (256 * 128) + coff;
        uint2 pv0 = *reinterpret_cast<const uint2*>(chunk + (g0 * 16 + r_) * 4);
        uint2 pv1 = *reinterpret_cast<const uint2*>(chunk + ((g0 + 1) * 16 + r_) * 4);
        acc[0] += bf2f_lo(pv0.x); acc[1] += bf2f_hi(pv0.x);
        acc[2] += bf2f_lo(pv0.y); acc[3] += bf2f_hi(pv0.y);
        acc[4] += bf2f_lo(pv1.x); acc[5] += bf2f_hi(pv1.x);
        acc[6] += bf2f_lo(pv1.y); acc[7] += bf2f_hi(pv1.y);
    }
    float* op = out + (size_t)gr * D_OUT + c0;
    float4 v0, v1;
    v0.x = acc[0] * inv; v0.y = acc[1] * inv; v0.z = acc[2] * inv; v0.w = acc[3] * inv;
    v1.x = acc[4] * inv; v1.y = acc[5] * inv; v1.z = acc[6] * inv; v1.w = acc[7] * inv;
    *reinterpret_cast<float4*>(op) = v0;
    *reinterpret_cast<float4*>(op + 4) = v1;
}

extern "C" void kernel_launch(void* const* d_in, const int* in_sizes, int n_in,
                              void* d_out, int out_size, void* d_ws, size_t ws_size,
                              hipStream_t stream) {
    const float* x  = (const float*)d_in[0];
    const float* Wq = (const float*)d_in[1];
    const float* Wk = (const float*)d_in[2];
    const float* Wv = (const float*)d_in[3];
    float* out = (float*)d_out;

    // ws layout (u16): Q | K | V^T | W^T | Po | Pml
    u16* Qb = (u16*)d_ws;
    u16* Kb = Qb + (size_t)M_TOTAL * D_OUT;
    u16* Vt = Kb + (size_t)M_TOTAL * D_OUT;
    u16* Wt = Vt + (size_t)M_TOTAL * D_OUT;

    const unsigned long long base = (3ULL * M_TOTAL * D_OUT + 3ULL * D_OUT * D_IN) * 2ULL;
    const unsigned long long perP = 256ULL * 128 * 2 + 512ULL * 4; // Po (64KB) + Pml (2KB)
    const int nblk = NPROP * NB; // 460 partial slots
    const int mode = (ws_size >= base + (unsigned long long)nblk * perP) ? 1 : 0;

    u16* Po = Wt + (size_t)3 * D_OUT * D_IN;
    float* Pml = (float*)(Po + (size_t)nblk * (256 * 128));

    wt_kernel<<<72, 256, 0, stream>>>(Wq, Wk, Wv, Wt);
    qkv_kernel<<<dim3(128, 3), 512, 0, stream>>>(x, Wt, Qb, Kb, Vt);
    attn_kernel<<<mode ? 464 : 16 * NB, 512, 0, stream>>>(Qb, Kb, Vt, Po, Pml, out, mode);
    if (mode)
        merge_kernel<<<M_TOTAL / 16, 256, 0, stream>>>(Po, Pml, out);
}